// Round 1
// baseline (330.570 us; speedup 1.0000x reference)
//
#include <hip/hip_runtime.h>
#include <hip/hip_bf16.h>

#define TOK 4096
#define DIM 1024
#define HID 2048
#define LN10K 9.210340371976184f

typedef __bf16 bh;
typedef __bf16 v8bf __attribute__((ext_vector_type(8)));
typedef float v4f __attribute__((ext_vector_type(4)));

typedef const __attribute__((address_space(1))) void* gvp;
typedef __attribute__((address_space(3))) void* svp;

__device__ __forceinline__ void gl_lds16(const bh* g, bh* s) {
  __builtin_amdgcn_global_load_lds((gvp)g, (svp)s, 16, 0, 0);
}

// ---------------- prep: cast X -> feat left half, colsum(E) ----------------
__global__ __launch_bounds__(256) void prep_x_colsum(const float* __restrict__ X,
                                                     bh* __restrict__ featb,
                                                     float* __restrict__ S) {
  int cp = blockIdx.x * 256 + threadIdx.x;      // column pair 0..511
  int c = cp * 2;
  int r0 = blockIdx.y * 16;
  float inv_denom = __expf(-(float)c * (LN10K / (float)DIM));
  float s0 = 0.f, s1 = 0.f;
#pragma unroll 4
  for (int r = r0; r < r0 + 16; ++r) {
    float2 x = *(const float2*)(X + (size_t)r * DIM + c);
    float sn, cs;
    __sincosf((float)r * inv_denom, &sn, &cs);
    s0 += sn * x.x;
    s1 += cs * x.y;
    bh pair[2] = {(bh)x.x, (bh)x.y};
    *(ushort2*)(featb + (size_t)r * (2 * DIM) + c) = *(ushort2*)pair;
  }
  atomicAdd(&S[c], s0);
  atomicAdd(&S[c + 1], s1);
}

// ---------------- prep: loo -> feat right half ----------------
__global__ __launch_bounds__(256) void prep_loo(const float* __restrict__ X,
                                                const float* __restrict__ S,
                                                bh* __restrict__ featb) {
  size_t e4 = ((size_t)blockIdx.x * 256 + threadIdx.x) * 4;  // over TOK*DIM
  int r = (int)(e4 >> 10);
  int c = (int)(e4 & 1023);
  float4 x = *(const float4*)(X + e4);
  float4 s = *(const float4*)(S + c);
  float id0 = __expf(-(float)c * (LN10K / (float)DIM));
  float id1 = __expf(-(float)(c + 2) * (LN10K / (float)DIM));
  float sn0, cs0, sn1, cs1;
  __sincosf((float)r * id0, &sn0, &cs0);
  __sincosf((float)r * id1, &sn1, &cs1);
  const float inv = 1.0f / (float)(TOK - 1);
  bh outv[4];
  outv[0] = (bh)((s.x - sn0 * x.x) * inv);
  outv[1] = (bh)((s.y - cs0 * x.y) * inv);
  outv[2] = (bh)((s.z - sn1 * x.z) * inv);
  outv[3] = (bh)((s.w - cs1 * x.w) * inv);
  *(ushort4*)(featb + (size_t)r * (2 * DIM) + DIM + c) = *(ushort4*)outv;
}

// ---------------- fused transpose+cast of all 3 weights (1 dispatch) -------
__global__ __launch_bounds__(256) void transpose_all(const float* __restrict__ Wv,
                                                     const float* __restrict__ W1,
                                                     const float* __restrict__ W2,
                                                     bh* __restrict__ WvT,
                                                     bh* __restrict__ W1T,
                                                     bh* __restrict__ W2T) {
  __shared__ float tile[32][33];
  int bid = blockIdx.x;
  const float* in; bh* out; int Ncol, R, bx, by;
  if (bid < 1024)      { in = Wv; out = WvT; Ncol = DIM; R = DIM;
                         bx = bid & 31; by = bid >> 5; }
  else if (bid < 5120) { int b = bid - 1024; in = W1; out = W1T; Ncol = HID; R = 2 * DIM;
                         bx = b & 63; by = b >> 6; }
  else                 { int b = bid - 5120; in = W2; out = W2T; Ncol = TOK; R = HID;
                         bx = b & 127; by = b >> 7; }
  int nb = bx * 32, rb = by * 32;
  int tx = threadIdx.x, ty = threadIdx.y;  // block (32,8)
#pragma unroll
  for (int j = 0; j < 32; j += 8)
    tile[ty + j][tx] = in[(size_t)(rb + ty + j) * Ncol + nb + tx];
  __syncthreads();
#pragma unroll
  for (int j = 0; j < 32; j += 8)
    out[(size_t)(nb + ty + j) * R + rb + tx] = (bh)tile[tx][ty + j];
}

// ---------------- GEMM: C = act(A @ BT^T + bias), 16x16x32 MFMA ------------
// (m97-class structure; still used for the smaller GEMMs this round)
template <int BN, bool RELU, bool TROUT, bool EXPS, typename OutT>
__global__ __launch_bounds__(128, 2) void gemm_bt(const bh* __restrict__ A,
                                                  const bh* __restrict__ BT,
                                                  const float* __restrict__ bias,
                                                  OutT* __restrict__ C,
                                                  float* __restrict__ rowsum,
                                                  int K, int lda, int ldbt, int ldc) {
  constexpr int NT = BN / 16;          // 8 (BN=128) or 4 (BN=64)
  __shared__ bh As[128 * 64];          // 16 KB
  __shared__ bh Bs[BN * 64];           // 16 or 8 KB
  const int t = threadIdx.x;
  const int id = blockIdx.x;
  const int bm = (id & 31) * 128, bn = (id >> 5) * BN;

  const int sr = t >> 3;               // staging row-in-group
  const int c8 = ((t & 7) ^ (sr & 7)) * 8;
  const bh* gA = A + (size_t)(bm + sr) * lda + c8;
  const bh* gB = BT + (size_t)(bn + sr) * ldbt + c8;
  bh* sA = As + t * 8;
  bh* sB = Bs + t * 8;

  const int lane = t & 63, w = t >> 6;
  const int lc = lane & 15, q = lane >> 4;

  v4f acc[4][NT] = {};
  for (int k0 = 0; k0 < K; k0 += 64) {
#pragma unroll
    for (int j = 0; j < 8; ++j)
      gl_lds16(gA + k0 + j * 16 * lda, sA + j * 1024);
#pragma unroll
    for (int j = 0; j < NT; ++j)
      gl_lds16(gB + k0 + j * 16 * ldbt, sB + j * 1024);
    __syncthreads();
#pragma unroll
    for (int h = 0; h < 2; ++h) {
      const int off = ((h * 4 + q) ^ (lc & 7)) * 8;
      v8bf af[4], bfr[NT];
#pragma unroll
      for (int mt = 0; mt < 4; ++mt)
        af[mt] = *(const v8bf*)(As + (w * 64 + mt * 16 + lc) * 64 + off);
#pragma unroll
      for (int nt = 0; nt < NT; ++nt)
        bfr[nt] = *(const v8bf*)(Bs + (nt * 16 + lc) * 64 + off);
#pragma unroll
      for (int mt = 0; mt < 4; ++mt)
#pragma unroll
        for (int nt = 0; nt < NT; ++nt)
          acc[mt][nt] = __builtin_amdgcn_mfma_f32_16x16x32_bf16(af[mt], bfr[nt], acc[mt][nt], 0, 0, 0);
    }
    __syncthreads();
  }

  // C/D layout: col = lane&15, row = q*4 + r  (m89-verified)
  const int r4 = q * 4;
  if (EXPS) {
    float bbv[NT];
#pragma unroll
    for (int nt = 0; nt < NT; ++nt) bbv[nt] = bias ? bias[bn + nt * 16 + lc] : 0.0f;
#pragma unroll
    for (int mt = 0; mt < 4; ++mt) {
#pragma unroll
      for (int r = 0; r < 4; ++r) {
        int row = bm + w * 64 + mt * 16 + r4 + r;
        float rs = 0.0f;
#pragma unroll
        for (int nt = 0; nt < NT; ++nt) {
          float val = __expf(acc[mt][nt][r] + bbv[nt]);
          rs += val;
          C[(size_t)row * ldc + bn + nt * 16 + lc] = (OutT)val;
        }
        rs += __shfl_xor(rs, 1);
        rs += __shfl_xor(rs, 2);
        rs += __shfl_xor(rs, 4);
        rs += __shfl_xor(rs, 8);
        if (lc == 0) atomicAdd(rowsum + row, rs);
      }
    }
  } else {
#pragma unroll
    for (int mt = 0; mt < 4; ++mt) {
      int row0 = bm + w * 64 + mt * 16 + r4;
#pragma unroll
      for (int nt = 0; nt < NT; ++nt) {
        int col = bn + nt * 16 + lc;
        float bb = bias ? bias[col] : 0.0f;
#pragma unroll
        for (int r = 0; r < 4; ++r) {
          float val = acc[mt][nt][r] + bb;
          if (RELU) val = fmaxf(val, 0.0f);
          if (TROUT) C[(size_t)col * ldc + (row0 + r)] = (OutT)val;
          else       C[(size_t)(row0 + r) * ldc + col] = (OutT)val;
        }
      }
    }
  }
}

// ---------------- gemm_exp256: scr = exp(hid @ W2T^T + b2) -----------------
// 256x256 tile, 8 waves (2Mx4N), wave tile 128x64, BK=32.
// Deep pipeline (T3+T4+T5): 3 LDS buffers, prefetch distance 2 K-tiles,
// raw s_barrier + counted s_waitcnt vmcnt(4) (never 0 in steady state),
// setprio(1) around MFMA clusters. 2 quadrant-phases per K-tile (16 MFMA ea).
// Swizzle: 16B chunks, chunk ^= (row>>1)&3 within each 64B row; applied to
// the GLOBAL source (lane-linear gl_lds dest) and to the ds_read address
// (both-sides rule, m104/m231). Per-16-lane aliasing is 2-way max (free).
// vmcnt ledger: prologue issues 8 (tiles 0,1), vmcnt(4) retires tile 0.
// Each iter kt<62 issues 4 (tile kt+2); end-of-iter vmcnt(4) retires tile
// kt+1. kt==62: no issue, vmcnt(0) retires tile 63. No other vmem in loop.
__global__ __launch_bounds__(512, 2) void gemm_exp256(const bh* __restrict__ A,
                                                      const bh* __restrict__ BT,
                                                      const float* __restrict__ bias,
                                                      bh* __restrict__ C,
                                                      float* __restrict__ rowsum) {
  __shared__ bh As[3 * 8192];          // 3 x 256rows x 32cols = 48 KB
  __shared__ bh Bs[3 * 8192];          // 48 KB
  const int t = threadIdx.x;
  const int id = blockIdx.x;           // 0..255, grid == CU count
  const int bm = (id & 15) * 256, bn = (id >> 4) * 256;
  const int lane = t & 63, w = t >> 6;
  const int wm = (w >> 2) * 128, wn = (w & 3) * 64;
  const int lc = lane & 15, q = lane >> 4;
  const int csw = (q ^ ((lc >> 1) & 3)) * 8;   // swizzled ds_read chunk (elems)

  // staging: 512 thr x 16B = 128 rows/round, 2 rounds per matrix per tile
  const int srow = t >> 2;                     // 0..127
  const int sc = (t & 3) ^ ((t >> 3) & 3);     // inverse-swizzled source chunk
  const bh* gA = A + (size_t)(bm + srow) * HID + sc * 8;
  const bh* gB = BT + (size_t)(bn + srow) * HID + sc * 8;
  bh* sA = As + t * 8;
  bh* sB = Bs + t * 8;

  auto stage_a = [&](int kt, int buf) {
    const bh* g = gA + (size_t)kt * 32;
    bh* s = sA + buf * 8192;
    gl_lds16(g, s);
    gl_lds16(g + (size_t)128 * HID, s + 4096);
  };
  auto stage_b = [&](int kt, int buf) {
    const bh* g = gB + (size_t)kt * 32;
    bh* s = sB + buf * 8192;
    gl_lds16(g, s);
    gl_lds16(g + (size_t)128 * HID, s + 4096);
  };

  v4f acc[8][4] = {};

  // prologue: tiles 0 -> buf0, 1 -> buf1; wait tile 0 only
  stage_a(0, 0); stage_b(0, 0);
  stage_a(1, 1); stage_b(1, 1);
  asm volatile("s_waitcnt vmcnt(4)" ::: "memory");
  __builtin_amdgcn_s_barrier();
  __builtin_amdgcn_sched_barrier(0);

  int cur = 0, nxt = 2;
  for (int kt = 0; kt < 64; ++kt) {
    const bh* ab = As + cur * 8192;
    const bh* bb = Bs + cur * 8192;
    // ---- phase 1: quadrant (m-lo x n-all) ----
    v8bf af[4], bf[4];
#pragma unroll
    for (int mt = 0; mt < 4; ++mt)
      af[mt] = *(const v8bf*)(ab + (wm + mt * 16 + lc) * 32 + csw);
#pragma unroll
    for (int nt = 0; nt < 4; ++nt)
      bf[nt] = *(const v8bf*)(bb + (wn + nt * 16 + lc) * 32 + csw);
    if (kt < 62) stage_a(kt + 2, nxt);
    __builtin_amdgcn_s_barrier();
    __builtin_amdgcn_sched_barrier(0);
    __builtin_amdgcn_s_setprio(1);
#pragma unroll
    for (int mt = 0; mt < 4; ++mt)
#pragma unroll
      for (int nt = 0; nt < 4; ++nt)
        acc[mt][nt] = __builtin_amdgcn_mfma_f32_16x16x32_bf16(af[mt], bf[nt], acc[mt][nt], 0, 0, 0);
    __builtin_amdgcn_s_setprio(0);
    __builtin_amdgcn_s_barrier();
    __builtin_amdgcn_sched_barrier(0);
    // ---- phase 2: quadrant (m-hi x n-all), B frags reused from regs ----
    v8bf ah[4];
#pragma unroll
    for (int mt = 0; mt < 4; ++mt)
      ah[mt] = *(const v8bf*)(ab + (wm + 64 + mt * 16 + lc) * 32 + csw);
    if (kt < 62) stage_b(kt + 2, nxt);
    __builtin_amdgcn_s_barrier();
    __builtin_amdgcn_sched_barrier(0);
    __builtin_amdgcn_s_setprio(1);
#pragma unroll
    for (int mt = 0; mt < 4; ++mt)
#pragma unroll
      for (int nt = 0; nt < 4; ++nt)
        acc[4 + mt][nt] = __builtin_amdgcn_mfma_f32_16x16x32_bf16(ah[mt], bf[nt], acc[4 + mt][nt], 0, 0, 0);
    __builtin_amdgcn_s_setprio(0);
    if (kt < 62)       asm volatile("s_waitcnt vmcnt(4)" ::: "memory");
    else if (kt == 62) asm volatile("s_waitcnt vmcnt(0)" ::: "memory");
    __builtin_amdgcn_s_barrier();
    __builtin_amdgcn_sched_barrier(0);
    cur = (cur == 2) ? 0 : cur + 1;
    nxt = (nxt == 2) ? 0 : nxt + 1;
  }

  // epilogue: val = exp(acc + bias); store bf16; rowsum via 16-lane reduce
  const int r4 = q * 4;
  float bbv[4];
#pragma unroll
  for (int nt = 0; nt < 4; ++nt) bbv[nt] = bias[bn + wn + nt * 16 + lc];
#pragma unroll
  for (int mt = 0; mt < 8; ++mt) {
#pragma unroll
    for (int r = 0; r < 4; ++r) {
      int row = bm + wm + mt * 16 + r4 + r;
      float rs = 0.0f;
#pragma unroll
      for (int nt = 0; nt < 4; ++nt) {
        float val = __expf(acc[mt][nt][r] + bbv[nt]);
        rs += val;
        C[(size_t)row * TOK + bn + wn + nt * 16 + lc] = (bh)val;
      }
      rs += __shfl_xor(rs, 1);
      rs += __shfl_xor(rs, 2);
      rs += __shfl_xor(rs, 4);
      rs += __shfl_xor(rs, 8);
      if (lc == 0) atomicAdd(rowsum + row, rs);
    }
  }
}

// ---------------- GEMM4: part = expP @ V via split-K, 16x16x32 -------------
// 256-thread blocks (2x2 waves of 64x64), tile 128x128, BK=64, split-K=2.
__global__ __launch_bounds__(256, 4) void gemm4_split(const bh* __restrict__ A,
                                                      const bh* __restrict__ BT,
                                                      float* __restrict__ C0,
                                                      float* __restrict__ C1) {
  __shared__ bh As[128 * 64];          // 16 KB
  __shared__ bh Bs[128 * 64];          // 16 KB
  const int t = threadIdx.x;
  const int id = blockIdx.x;           // 0..255
  const int bm = (id & 31) * 128, bn = (id >> 5) * 128;
  const int kbeg = blockIdx.y * (TOK / 2);

  const int sr = t >> 3;               // 0..31
  const int c8 = ((t & 7) ^ (sr & 7)) * 8;
  const bh* gA = A + (size_t)(bm + sr) * TOK + kbeg + c8;
  const bh* gB = BT + (size_t)(bn + sr) * TOK + kbeg + c8;
  bh* sA = As + t * 8;
  bh* sB = Bs + t * 8;

  const int lane = t & 63, w = t >> 6;
  const int wm = (w >> 1) * 64, wn = (w & 1) * 64;
  const int lc = lane & 15, q = lane >> 4;

  v4f acc[4][4] = {};
  for (int k0 = 0; k0 < TOK / 2; k0 += 64) {
#pragma unroll
    for (int j = 0; j < 4; ++j) {
      gl_lds16(gA + k0 + (size_t)(j * 32) * TOK, sA + j * 2048);
      gl_lds16(gB + k0 + (size_t)(j * 32) * TOK, sB + j * 2048);
    }
    __syncthreads();
#pragma unroll
    for (int h = 0; h < 2; ++h) {
      const int off = ((h * 4 + q) ^ (lc & 7)) * 8;
      v8bf af[4], bfr[4];
#pragma unroll
      for (int mt = 0; mt < 4; ++mt)
        af[mt] = *(const v8bf*)(As + (wm + mt * 16 + lc) * 64 + off);
#pragma unroll
      for (int nt = 0; nt < 4; ++nt)
        bfr[nt] = *(const v8bf*)(Bs + (wn + nt * 16 + lc) * 64 + off);
#pragma unroll
      for (int mt = 0; mt < 4; ++mt)
#pragma unroll
        for (int nt = 0; nt < 4; ++nt)
          acc[mt][nt] = __builtin_amdgcn_mfma_f32_16x16x32_bf16(af[mt], bfr[nt], acc[mt][nt], 0, 0, 0);
    }
    __syncthreads();
  }

  float* C = blockIdx.y ? C1 : C0;
  const int r4 = q * 4;
#pragma unroll
  for (int mt = 0; mt < 4; ++mt) {
    int row0 = bm + wm + mt * 16 + r4;
#pragma unroll
    for (int nt = 0; nt < 4; ++nt) {
      int col = bn + wn + nt * 16 + lc;
#pragma unroll
      for (int r = 0; r < 4; ++r)
        C[(size_t)(row0 + r) * DIM + col] = acc[mt][nt][r];
    }
  }
}

// ---------------- finalize: out = (p0 + p1) / rowsum[row] ------------------
__global__ __launch_bounds__(256) void finalize(const float* __restrict__ p0,
                                                const float* __restrict__ p1,
                                                const float* __restrict__ rowsum,
                                                float* __restrict__ out) {
  size_t i = ((size_t)blockIdx.x * 256 + threadIdx.x) * 4;
  int row = (int)(i >> 10);            // DIM = 1024
  float inv = 1.0f / rowsum[row];
  float4 a = *(const float4*)(p0 + i);
  float4 b = *(const float4*)(p1 + i);
  float4 o;
  o.x = (a.x + b.x) * inv; o.y = (a.y + b.y) * inv;
  o.z = (a.z + b.z) * inv; o.w = (a.w + b.w) * inv;
  *(float4*)(out + i) = o;
}

extern "C" void kernel_launch(void* const* d_in, const int* in_sizes, int n_in,
                              void* d_out, int out_size, void* d_ws, size_t ws_size,
                              hipStream_t stream) {
  (void)in_sizes; (void)n_in; (void)out_size; (void)ws_size;
  const float* X  = (const float*)d_in[0];
  // d_in[1] = mask, unused by the module
  const float* Wv = (const float*)d_in[2];
  const float* bv = (const float*)d_in[3];
  const float* W1 = (const float*)d_in[4];
  const float* b1 = (const float*)d_in[5];
  const float* W2 = (const float*)d_in[6];
  const float* b2 = (const float*)d_in[7];
  float* out = (float*)d_out;

  char* ws = (char*)d_ws;
  bh* featb = (bh*)(ws);                       // 4096 x 2048 bf16 : 16 MiB
  bh* WvT   = (bh*)(ws + (16u << 20));         // 1024 x 1024      :  2 MiB
  bh* W1T   = (bh*)(ws + (18u << 20));         // 2048 x 2048      :  8 MiB
  bh* W2T   = (bh*)(ws + (26u << 20));         // 4096 x 2048      : 16 MiB
  bh* Vt    = (bh*)(ws + (42u << 20));         // 1024 x 4096      :  8 MiB
  bh* hid   = (bh*)(ws + (50u << 20));         // 4096 x 2048      : 16 MiB
  bh* scr   = (bh*)(ws + (66u << 20));         // 4096 x 4096 bf16 : 32 MiB (exp scores)
  float* S  = (float*)(ws + (98u << 20));      // 1024 fp32 (4 KB)
  float* rowsum = (float*)(ws + (98u << 20) + 4096);  // 4096 fp32 (16 KB)
  // split-K partials: part0 reuses featb region (dead after gemm2),
  // part1 reuses W2T region (dead after gemm3). 16 MiB fp32 each.
  float* part0 = (float*)(ws);
  float* part1 = (float*)(ws + (26u << 20));

  hipError_t e = hipMemsetAsync(S, 0, 4096 + 4096 * sizeof(float), stream);
  (void)e;
  prep_x_colsum<<<dim3(DIM / 512, TOK / 16), 256, 0, stream>>>(X, featb, S);
  prep_loo<<<dim3((TOK * DIM) / 1024), 256, 0, stream>>>(X, S, featb);
  transpose_all<<<dim3(1024 + 4096 + 8192), dim3(32, 8), 0, stream>>>(
      Wv, W1, W2, WvT, W1T, W2T);

  // V^T = (feat_left @ Wv + bv)^T  -> Vt (1024 x 4096, ld 4096)
  gemm_bt<64, false, true, false, bh><<<dim3(32 * (DIM / 64)), 128, 0, stream>>>(
      featb, WvT, bv, Vt, nullptr, DIM, 2 * DIM, DIM, TOK);
  // hid = relu(feat @ W1 + b1)
  gemm_bt<128, true, false, false, bh><<<dim3(32 * (HID / 128)), 128, 0, stream>>>(
      featb, W1T, b1, hid, nullptr, 2 * DIM, 2 * DIM, 2 * DIM, HID);
  // scr = exp(hid @ W2 + b2) [unnormalized softmax numerator] + rowsum
  // 256^2-tile deep-pipelined kernel: grid 256 == CU count, 512 thr, 96KB LDS
  gemm_exp256<<<dim3(256), 512, 0, stream>>>(hid, W2T, b2, scr, rowsum);
  // parts = scr @ V, split-K=2
  gemm4_split<<<dim3(256, 2), 256, 0, stream>>>(scr, Vt, part0, part1);
  // out = (part0 + part1) / rowsum
  finalize<<<dim3((TOK * DIM) / 1024), 256, 0, stream>>>(part0, part1, rowsum, out);
}

// Round 2
// 328.204 us; speedup vs baseline: 1.0072x; 1.0072x over previous
//
#include <hip/hip_runtime.h>
#include <hip/hip_bf16.h>

#define TOK 4096
#define DIM 1024
#define HID 2048
#define LN10K 9.210340371976184f

typedef __bf16 bh;
typedef __bf16 v8bf __attribute__((ext_vector_type(8)));
typedef float v4f __attribute__((ext_vector_type(4)));

typedef const __attribute__((address_space(1))) void* gvp;
typedef __attribute__((address_space(3))) void* svp;

__device__ __forceinline__ void gl_lds16(const bh* g, bh* s) {
  __builtin_amdgcn_global_load_lds((gvp)g, (svp)s, 16, 0, 0);
}

// ---------------- prep: cast X -> feat left half, colsum(E) ----------------
__global__ __launch_bounds__(256) void prep_x_colsum(const float* __restrict__ X,
                                                     bh* __restrict__ featb,
                                                     float* __restrict__ S) {
  int cp = blockIdx.x * 256 + threadIdx.x;      // column pair 0..511
  int c = cp * 2;
  int r0 = blockIdx.y * 16;
  float inv_denom = __expf(-(float)c * (LN10K / (float)DIM));
  float s0 = 0.f, s1 = 0.f;
#pragma unroll 4
  for (int r = r0; r < r0 + 16; ++r) {
    float2 x = *(const float2*)(X + (size_t)r * DIM + c);
    float sn, cs;
    __sincosf((float)r * inv_denom, &sn, &cs);
    s0 += sn * x.x;
    s1 += cs * x.y;
    bh pair[2] = {(bh)x.x, (bh)x.y};
    *(ushort2*)(featb + (size_t)r * (2 * DIM) + c) = *(ushort2*)pair;
  }
  atomicAdd(&S[c], s0);
  atomicAdd(&S[c + 1], s1);
}

// ---------------- prep: loo -> feat right half ----------------
__global__ __launch_bounds__(256) void prep_loo(const float* __restrict__ X,
                                                const float* __restrict__ S,
                                                bh* __restrict__ featb) {
  size_t e4 = ((size_t)blockIdx.x * 256 + threadIdx.x) * 4;  // over TOK*DIM
  int r = (int)(e4 >> 10);
  int c = (int)(e4 & 1023);
  float4 x = *(const float4*)(X + e4);
  float4 s = *(const float4*)(S + c);
  float id0 = __expf(-(float)c * (LN10K / (float)DIM));
  float id1 = __expf(-(float)(c + 2) * (LN10K / (float)DIM));
  float sn0, cs0, sn1, cs1;
  __sincosf((float)r * id0, &sn0, &cs0);
  __sincosf((float)r * id1, &sn1, &cs1);
  const float inv = 1.0f / (float)(TOK - 1);
  bh outv[4];
  outv[0] = (bh)((s.x - sn0 * x.x) * inv);
  outv[1] = (bh)((s.y - cs0 * x.y) * inv);
  outv[2] = (bh)((s.z - sn1 * x.z) * inv);
  outv[3] = (bh)((s.w - cs1 * x.w) * inv);
  *(ushort4*)(featb + (size_t)r * (2 * DIM) + DIM + c) = *(ushort4*)outv;
}

// ---------------- fused transpose+cast of all 3 weights (1 dispatch) -------
__global__ __launch_bounds__(256) void transpose_all(const float* __restrict__ Wv,
                                                     const float* __restrict__ W1,
                                                     const float* __restrict__ W2,
                                                     bh* __restrict__ WvT,
                                                     bh* __restrict__ W1T,
                                                     bh* __restrict__ W2T) {
  __shared__ float tile[32][33];
  int bid = blockIdx.x;
  const float* in; bh* out; int Ncol, R, bx, by;
  if (bid < 1024)      { in = Wv; out = WvT; Ncol = DIM; R = DIM;
                         bx = bid & 31; by = bid >> 5; }
  else if (bid < 5120) { int b = bid - 1024; in = W1; out = W1T; Ncol = HID; R = 2 * DIM;
                         bx = b & 63; by = b >> 6; }
  else                 { int b = bid - 5120; in = W2; out = W2T; Ncol = TOK; R = HID;
                         bx = b & 127; by = b >> 7; }
  int nb = bx * 32, rb = by * 32;
  int tx = threadIdx.x, ty = threadIdx.y;  // block (32,8)
#pragma unroll
  for (int j = 0; j < 32; j += 8)
    tile[ty + j][tx] = in[(size_t)(rb + ty + j) * Ncol + nb + tx];
  __syncthreads();
#pragma unroll
  for (int j = 0; j < 32; j += 8)
    out[(size_t)(nb + ty + j) * R + rb + tx] = (bh)tile[tx][ty + j];
}

// ---------------- GEMM: C = act(A @ BT^T + bias), 16x16x32 MFMA ------------
// (m97-class structure; still used for the smaller GEMMs this round)
template <int BN, bool RELU, bool TROUT, bool EXPS, typename OutT>
__global__ __launch_bounds__(128, 2) void gemm_bt(const bh* __restrict__ A,
                                                  const bh* __restrict__ BT,
                                                  const float* __restrict__ bias,
                                                  OutT* __restrict__ C,
                                                  float* __restrict__ rowsum,
                                                  int K, int lda, int ldbt, int ldc) {
  constexpr int NT = BN / 16;          // 8 (BN=128) or 4 (BN=64)
  __shared__ bh As[128 * 64];          // 16 KB
  __shared__ bh Bs[BN * 64];           // 16 or 8 KB
  const int t = threadIdx.x;
  const int id = blockIdx.x;
  const int bm = (id & 31) * 128, bn = (id >> 5) * BN;

  const int sr = t >> 3;               // staging row-in-group
  const int c8 = ((t & 7) ^ (sr & 7)) * 8;
  const bh* gA = A + (size_t)(bm + sr) * lda + c8;
  const bh* gB = BT + (size_t)(bn + sr) * ldbt + c8;
  bh* sA = As + t * 8;
  bh* sB = Bs + t * 8;

  const int lane = t & 63, w = t >> 6;
  const int lc = lane & 15, q = lane >> 4;

  v4f acc[4][NT] = {};
  for (int k0 = 0; k0 < K; k0 += 64) {
#pragma unroll
    for (int j = 0; j < 8; ++j)
      gl_lds16(gA + k0 + j * 16 * lda, sA + j * 1024);
#pragma unroll
    for (int j = 0; j < NT; ++j)
      gl_lds16(gB + k0 + j * 16 * ldbt, sB + j * 1024);
    __syncthreads();
#pragma unroll
    for (int h = 0; h < 2; ++h) {
      const int off = ((h * 4 + q) ^ (lc & 7)) * 8;
      v8bf af[4], bfr[NT];
#pragma unroll
      for (int mt = 0; mt < 4; ++mt)
        af[mt] = *(const v8bf*)(As + (w * 64 + mt * 16 + lc) * 64 + off);
#pragma unroll
      for (int nt = 0; nt < NT; ++nt)
        bfr[nt] = *(const v8bf*)(Bs + (nt * 16 + lc) * 64 + off);
#pragma unroll
      for (int mt = 0; mt < 4; ++mt)
#pragma unroll
        for (int nt = 0; nt < NT; ++nt)
          acc[mt][nt] = __builtin_amdgcn_mfma_f32_16x16x32_bf16(af[mt], bfr[nt], acc[mt][nt], 0, 0, 0);
    }
    __syncthreads();
  }

  // C/D layout: col = lane&15, row = q*4 + r  (m89-verified)
  const int r4 = q * 4;
  if (EXPS) {
    float bbv[NT];
#pragma unroll
    for (int nt = 0; nt < NT; ++nt) bbv[nt] = bias ? bias[bn + nt * 16 + lc] : 0.0f;
#pragma unroll
    for (int mt = 0; mt < 4; ++mt) {
#pragma unroll
      for (int r = 0; r < 4; ++r) {
        int row = bm + w * 64 + mt * 16 + r4 + r;
        float rs = 0.0f;
#pragma unroll
        for (int nt = 0; nt < NT; ++nt) {
          float val = __expf(acc[mt][nt][r] + bbv[nt]);
          rs += val;
          C[(size_t)row * ldc + bn + nt * 16 + lc] = (OutT)val;
        }
        rs += __shfl_xor(rs, 1);
        rs += __shfl_xor(rs, 2);
        rs += __shfl_xor(rs, 4);
        rs += __shfl_xor(rs, 8);
        if (lc == 0) atomicAdd(rowsum + row, rs);
      }
    }
  } else {
#pragma unroll
    for (int mt = 0; mt < 4; ++mt) {
      int row0 = bm + w * 64 + mt * 16 + r4;
#pragma unroll
      for (int nt = 0; nt < NT; ++nt) {
        int col = bn + nt * 16 + lc;
        float bb = bias ? bias[col] : 0.0f;
#pragma unroll
        for (int r = 0; r < 4; ++r) {
          float val = acc[mt][nt][r] + bb;
          if (RELU) val = fmaxf(val, 0.0f);
          if (TROUT) C[(size_t)col * ldc + (row0 + r)] = (OutT)val;
          else       C[(size_t)(row0 + r) * ldc + col] = (OutT)val;
        }
      }
    }
  }
}

// ---------------- gemm_exp256: scr = exp(hid @ W2T^T + b2) -----------------
// 256x256 tile, 8 waves (2Mx4N), wave tile 128x64, BK=32, 64 K-tiles.
// T4 pipeline, compiler-scheduled (m141 lesson: NO sched_barrier pins):
//   - 4 LDS slots (4 x 16KB A + 4 x 16KB B = 128 KB), prefetch distance 2,
//     K-loop unrolled x4 so slot indices are compile-time constants.
//   - ONE raw s_barrier + ONE counted vmcnt per K-tile; vmcnt(4) in steady
//     state (never 0 until the kt=62 tail) so 4-8 loads stay in flight
//     across barriers.
//   - setprio(1) around the 32-MFMA cluster (T5).
// vmcnt ledger (per wave, 4 gl_lds per tile): prologue stages t0,t1 (8),
// vmcnt(4) retires t0. Tile kt stages kt+2 (8 in flight), vmcnt(4) retires
// kt+1 before the barrier; next tile reads slot (kt+1)&3. kt=62: vmcnt(0)
// retires t63. Slot-overwrite safety: stage at kt targets slot (kt+2)&3 =
// (kt-2)&3, last read at tile kt-2, two barriers earlier; wave skew <= 1
// tile, so no wave can still be reading it.
// Swizzle (0 conflicts measured r1): global source chunk (t&3)^((t>>3)&3),
// lane-linear LDS dest; ds_read chunk q^((lc>>1)&3) — same involution.
__global__ __launch_bounds__(512, 2) void gemm_exp256(const bh* __restrict__ A,
                                                      const bh* __restrict__ BT,
                                                      const float* __restrict__ bias,
                                                      bh* __restrict__ C,
                                                      float* __restrict__ rowsum) {
  __shared__ bh As[4 * 8192];          // 4 slots x 256rows x 32cols = 64 KB
  __shared__ bh Bs[4 * 8192];          // 64 KB
  const int t = threadIdx.x;
  const int id = blockIdx.x;           // 0..255, grid == CU count
  const int bm = (id & 15) * 256, bn = (id >> 4) * 256;
  const int lane = t & 63, w = t >> 6;
  const int wm = (w >> 2) * 128, wn = (w & 3) * 64;
  const int lc = lane & 15, q = lane >> 4;
  const int csw = (q ^ ((lc >> 1) & 3)) * 8;   // swizzled ds_read chunk (elems)

  // staging: 512 thr x 16B = 128 rows/instr, 2 instrs per matrix per tile
  const int srow = t >> 2;                     // 0..127
  const int sc = (t & 3) ^ ((t >> 3) & 3);     // inverse-swizzled source chunk
  const bh* gA = A + (size_t)(bm + srow) * HID + sc * 8;
  const bh* gB = BT + (size_t)(bn + srow) * HID + sc * 8;
  bh* sA = As + t * 8;
  bh* sB = Bs + t * 8;

  v4f acc[8][4] = {};

#define STAGE(kt, slot)                                                        \
  do {                                                                         \
    gl_lds16(gA + (kt) * 32, sA + (slot) * 8192);                              \
    gl_lds16(gA + (kt) * 32 + (size_t)128 * HID, sA + (slot) * 8192 + 4096);   \
    gl_lds16(gB + (kt) * 32, sB + (slot) * 8192);                              \
    gl_lds16(gB + (kt) * 32 + (size_t)128 * HID, sB + (slot) * 8192 + 4096);   \
  } while (0)

// WMODE: 1 = steady (vmcnt(4)+barrier), 2 = tail (vmcnt(0)+barrier), 0 = none
#define TILE(kt, slot, STG, WMODE)                                             \
  do {                                                                         \
    const bh* ab = As + (slot) * 8192;                                         \
    const bh* bb = Bs + (slot) * 8192;                                         \
    v8bf af[4], ah[4], bfr[4];                                                 \
    _Pragma("unroll") for (int mt = 0; mt < 4; ++mt)                           \
        af[mt] = *(const v8bf*)(ab + (wm + mt * 16 + lc) * 32 + csw);          \
    _Pragma("unroll") for (int nt = 0; nt < 4; ++nt)                           \
        bfr[nt] = *(const v8bf*)(bb + (wn + nt * 16 + lc) * 32 + csw);         \
    _Pragma("unroll") for (int mt = 0; mt < 4; ++mt)                           \
        ah[mt] = *(const v8bf*)(ab + (wm + 64 + mt * 16 + lc) * 32 + csw);     \
    if (STG) STAGE((kt) + 2, ((slot) + 2) & 3);                                \
    __builtin_amdgcn_s_setprio(1);                                             \
    _Pragma("unroll") for (int mt = 0; mt < 4; ++mt)                           \
        _Pragma("unroll") for (int nt = 0; nt < 4; ++nt)                       \
            acc[mt][nt] = __builtin_amdgcn_mfma_f32_16x16x32_bf16(             \
                af[mt], bfr[nt], acc[mt][nt], 0, 0, 0);                        \
    _Pragma("unroll") for (int mt = 0; mt < 4; ++mt)                           \
        _Pragma("unroll") for (int nt = 0; nt < 4; ++nt)                       \
            acc[4 + mt][nt] = __builtin_amdgcn_mfma_f32_16x16x32_bf16(         \
                ah[mt], bfr[nt], acc[4 + mt][nt], 0, 0, 0);                    \
    __builtin_amdgcn_s_setprio(0);                                             \
    if ((WMODE) == 1) asm volatile("s_waitcnt vmcnt(4)" ::: "memory");         \
    if ((WMODE) == 2) asm volatile("s_waitcnt vmcnt(0)" ::: "memory");         \
    if ((WMODE) != 0) __builtin_amdgcn_s_barrier();                            \
  } while (0)

  // prologue: tiles 0 -> slot0, 1 -> slot1; wait tile 0 only
  STAGE(0, 0);
  STAGE(1, 1);
  asm volatile("s_waitcnt vmcnt(4)" ::: "memory");
  __builtin_amdgcn_s_barrier();

  for (int ko = 0; ko < 15; ++ko) {
    const int kb = ko * 4;
    TILE(kb + 0, 0, true, 1);
    TILE(kb + 1, 1, true, 1);
    TILE(kb + 2, 2, true, 1);
    TILE(kb + 3, 3, true, 1);
  }
  TILE(60, 0, true, 1);
  TILE(61, 1, true, 1);   // stages tile 63 -> slot 3
  TILE(62, 2, false, 2);  // vmcnt(0): retire tile 63's loads
  TILE(63, 3, false, 0);  // last tile, no wait/barrier needed

#undef TILE
#undef STAGE

  // epilogue: val = exp(acc + bias); store bf16; rowsum via 16-lane reduce
  const int r4 = q * 4;
  float bbv[4];
#pragma unroll
  for (int nt = 0; nt < 4; ++nt) bbv[nt] = bias[bn + wn + nt * 16 + lc];
#pragma unroll
  for (int mt = 0; mt < 8; ++mt) {
#pragma unroll
    for (int r = 0; r < 4; ++r) {
      int row = bm + wm + mt * 16 + r4 + r;
      float rs = 0.0f;
#pragma unroll
      for (int nt = 0; nt < 4; ++nt) {
        float val = __expf(acc[mt][nt][r] + bbv[nt]);
        rs += val;
        C[(size_t)row * TOK + bn + wn + nt * 16 + lc] = (bh)val;
      }
      rs += __shfl_xor(rs, 1);
      rs += __shfl_xor(rs, 2);
      rs += __shfl_xor(rs, 4);
      rs += __shfl_xor(rs, 8);
      if (lc == 0) atomicAdd(rowsum + row, rs);
    }
  }
}

// ---------------- GEMM4: part = expP @ V via split-K, 16x16x32 -------------
// 256-thread blocks (2x2 waves of 64x64), tile 128x128, BK=64, split-K=2.
__global__ __launch_bounds__(256, 4) void gemm4_split(const bh* __restrict__ A,
                                                      const bh* __restrict__ BT,
                                                      float* __restrict__ C0,
                                                      float* __restrict__ C1) {
  __shared__ bh As[128 * 64];          // 16 KB
  __shared__ bh Bs[128 * 64];          // 16 KB
  const int t = threadIdx.x;
  const int id = blockIdx.x;           // 0..255
  const int bm = (id & 31) * 128, bn = (id >> 5) * 128;
  const int kbeg = blockIdx.y * (TOK / 2);

  const int sr = t >> 3;               // 0..31
  const int c8 = ((t & 7) ^ (sr & 7)) * 8;
  const bh* gA = A + (size_t)(bm + sr) * TOK + kbeg + c8;
  const bh* gB = BT + (size_t)(bn + sr) * TOK + kbeg + c8;
  bh* sA = As + t * 8;
  bh* sB = Bs + t * 8;

  const int lane = t & 63, w = t >> 6;
  const int wm = (w >> 1) * 64, wn = (w & 1) * 64;
  const int lc = lane & 15, q = lane >> 4;

  v4f acc[4][4] = {};
  for (int k0 = 0; k0 < TOK / 2; k0 += 64) {
#pragma unroll
    for (int j = 0; j < 4; ++j) {
      gl_lds16(gA + k0 + (size_t)(j * 32) * TOK, sA + j * 2048);
      gl_lds16(gB + k0 + (size_t)(j * 32) * TOK, sB + j * 2048);
    }
    __syncthreads();
#pragma unroll
    for (int h = 0; h < 2; ++h) {
      const int off = ((h * 4 + q) ^ (lc & 7)) * 8;
      v8bf af[4], bfr[4];
#pragma unroll
      for (int mt = 0; mt < 4; ++mt)
        af[mt] = *(const v8bf*)(As + (wm + mt * 16 + lc) * 64 + off);
#pragma unroll
      for (int nt = 0; nt < 4; ++nt)
        bfr[nt] = *(const v8bf*)(Bs + (wn + nt * 16 + lc) * 64 + off);
#pragma unroll
      for (int mt = 0; mt < 4; ++mt)
#pragma unroll
        for (int nt = 0; nt < 4; ++nt)
          acc[mt][nt] = __builtin_amdgcn_mfma_f32_16x16x32_bf16(af[mt], bfr[nt], acc[mt][nt], 0, 0, 0);
    }
    __syncthreads();
  }

  float* C = blockIdx.y ? C1 : C0;
  const int r4 = q * 4;
#pragma unroll
  for (int mt = 0; mt < 4; ++mt) {
    int row0 = bm + wm + mt * 16 + r4;
#pragma unroll
    for (int nt = 0; nt < 4; ++nt) {
      int col = bn + wn + nt * 16 + lc;
#pragma unroll
      for (int r = 0; r < 4; ++r)
        C[(size_t)(row0 + r) * DIM + col] = acc[mt][nt][r];
    }
  }
}

// ---------------- finalize: out = (p0 + p1) / rowsum[row] ------------------
__global__ __launch_bounds__(256) void finalize(const float* __restrict__ p0,
                                                const float* __restrict__ p1,
                                                const float* __restrict__ rowsum,
                                                float* __restrict__ out) {
  size_t i = ((size_t)blockIdx.x * 256 + threadIdx.x) * 4;
  int row = (int)(i >> 10);            // DIM = 1024
  float inv = 1.0f / rowsum[row];
  float4 a = *(const float4*)(p0 + i);
  float4 b = *(const float4*)(p1 + i);
  float4 o;
  o.x = (a.x + b.x) * inv; o.y = (a.y + b.y) * inv;
  o.z = (a.z + b.z) * inv; o.w = (a.w + b.w) * inv;
  *(float4*)(out + i) = o;
}

extern "C" void kernel_launch(void* const* d_in, const int* in_sizes, int n_in,
                              void* d_out, int out_size, void* d_ws, size_t ws_size,
                              hipStream_t stream) {
  (void)in_sizes; (void)n_in; (void)out_size; (void)ws_size;
  const float* X  = (const float*)d_in[0];
  // d_in[1] = mask, unused by the module
  const float* Wv = (const float*)d_in[2];
  const float* bv = (const float*)d_in[3];
  const float* W1 = (const float*)d_in[4];
  const float* b1 = (const float*)d_in[5];
  const float* W2 = (const float*)d_in[6];
  const float* b2 = (const float*)d_in[7];
  float* out = (float*)d_out;

  char* ws = (char*)d_ws;
  bh* featb = (bh*)(ws);                       // 4096 x 2048 bf16 : 16 MiB
  bh* WvT   = (bh*)(ws + (16u << 20));         // 1024 x 1024      :  2 MiB
  bh* W1T   = (bh*)(ws + (18u << 20));         // 2048 x 2048      :  8 MiB
  bh* W2T   = (bh*)(ws + (26u << 20));         // 4096 x 2048      : 16 MiB
  bh* Vt    = (bh*)(ws + (42u << 20));         // 1024 x 4096      :  8 MiB
  bh* hid   = (bh*)(ws + (50u << 20));         // 4096 x 2048      : 16 MiB
  bh* scr   = (bh*)(ws + (66u << 20));         // 4096 x 4096 bf16 : 32 MiB (exp scores)
  float* S  = (float*)(ws + (98u << 20));      // 1024 fp32 (4 KB)
  float* rowsum = (float*)(ws + (98u << 20) + 4096);  // 4096 fp32 (16 KB)
  // split-K partials: part0 reuses featb region (dead after gemm2),
  // part1 reuses W2T region (dead after gemm3). 16 MiB fp32 each.
  float* part0 = (float*)(ws);
  float* part1 = (float*)(ws + (26u << 20));

  hipError_t e = hipMemsetAsync(S, 0, 4096 + 4096 * sizeof(float), stream);
  (void)e;
  prep_x_colsum<<<dim3(DIM / 512, TOK / 16), 256, 0, stream>>>(X, featb, S);
  prep_loo<<<dim3((TOK * DIM) / 1024), 256, 0, stream>>>(X, S, featb);
  transpose_all<<<dim3(1024 + 4096 + 8192), dim3(32, 8), 0, stream>>>(
      Wv, W1, W2, WvT, W1T, W2T);

  // V^T = (feat_left @ Wv + bv)^T  -> Vt (1024 x 4096, ld 4096)
  gemm_bt<64, false, true, false, bh><<<dim3(32 * (DIM / 64)), 128, 0, stream>>>(
      featb, WvT, bv, Vt, nullptr, DIM, 2 * DIM, DIM, TOK);
  // hid = relu(feat @ W1 + b1)
  gemm_bt<128, true, false, false, bh><<<dim3(32 * (HID / 128)), 128, 0, stream>>>(
      featb, W1T, b1, hid, nullptr, 2 * DIM, 2 * DIM, 2 * DIM, HID);
  // scr = exp(hid @ W2 + b2) [unnormalized softmax numerator] + rowsum
  // 256^2-tile T4-pipelined kernel: grid 256 == CU count, 512 thr, 128KB LDS
  gemm_exp256<<<dim3(256), 512, 0, stream>>>(hid, W2T, b2, scr, rowsum);
  // parts = scr @ V, split-K=2
  gemm4_split<<<dim3(256, 2), 256, 0, stream>>>(scr, Vt, part0, part1);
  // out = (part0 + part1) / rowsum
  finalize<<<dim3((TOK * DIM) / 1024), 256, 0, stream>>>(part0, part1, rowsum, out);
}

// Round 3
// 327.462 us; speedup vs baseline: 1.0095x; 1.0023x over previous
//
#include <hip/hip_runtime.h>
#include <hip/hip_bf16.h>

#define TOK 4096
#define DIM 1024
#define HID 2048
#define LN10K 9.210340371976184f

typedef __bf16 bh;
typedef __bf16 v8bf __attribute__((ext_vector_type(8)));
typedef float v4f __attribute__((ext_vector_type(4)));

typedef const __attribute__((address_space(1))) void* gvp;
typedef __attribute__((address_space(3))) void* svp;

__device__ __forceinline__ void gl_lds16(const bh* g, bh* s) {
  __builtin_amdgcn_global_load_lds((gvp)g, (svp)s, 16, 0, 0);
}

// ---------------- prep: cast X -> feat left half, colsum(E) ----------------
__global__ __launch_bounds__(256) void prep_x_colsum(const float* __restrict__ X,
                                                     bh* __restrict__ featb,
                                                     float* __restrict__ S) {
  int cp = blockIdx.x * 256 + threadIdx.x;      // column pair 0..511
  int c = cp * 2;
  int r0 = blockIdx.y * 16;
  float inv_denom = __expf(-(float)c * (LN10K / (float)DIM));
  float s0 = 0.f, s1 = 0.f;
#pragma unroll 4
  for (int r = r0; r < r0 + 16; ++r) {
    float2 x = *(const float2*)(X + (size_t)r * DIM + c);
    float sn, cs;
    __sincosf((float)r * inv_denom, &sn, &cs);
    s0 += sn * x.x;
    s1 += cs * x.y;
    bh pair[2] = {(bh)x.x, (bh)x.y};
    *(ushort2*)(featb + (size_t)r * (2 * DIM) + c) = *(ushort2*)pair;
  }
  atomicAdd(&S[c], s0);
  atomicAdd(&S[c + 1], s1);
}

// ---------------- prep: loo -> feat right half ----------------
__global__ __launch_bounds__(256) void prep_loo(const float* __restrict__ X,
                                                const float* __restrict__ S,
                                                bh* __restrict__ featb) {
  size_t e4 = ((size_t)blockIdx.x * 256 + threadIdx.x) * 4;  // over TOK*DIM
  int r = (int)(e4 >> 10);
  int c = (int)(e4 & 1023);
  float4 x = *(const float4*)(X + e4);
  float4 s = *(const float4*)(S + c);
  float id0 = __expf(-(float)c * (LN10K / (float)DIM));
  float id1 = __expf(-(float)(c + 2) * (LN10K / (float)DIM));
  float sn0, cs0, sn1, cs1;
  __sincosf((float)r * id0, &sn0, &cs0);
  __sincosf((float)r * id1, &sn1, &cs1);
  const float inv = 1.0f / (float)(TOK - 1);
  bh outv[4];
  outv[0] = (bh)((s.x - sn0 * x.x) * inv);
  outv[1] = (bh)((s.y - cs0 * x.y) * inv);
  outv[2] = (bh)((s.z - sn1 * x.z) * inv);
  outv[3] = (bh)((s.w - cs1 * x.w) * inv);
  *(ushort4*)(featb + (size_t)r * (2 * DIM) + DIM + c) = *(ushort4*)outv;
}

// ---------------- fused transpose+cast of all 3 weights (1 dispatch) -------
__global__ __launch_bounds__(256) void transpose_all(const float* __restrict__ Wv,
                                                     const float* __restrict__ W1,
                                                     const float* __restrict__ W2,
                                                     bh* __restrict__ WvT,
                                                     bh* __restrict__ W1T,
                                                     bh* __restrict__ W2T) {
  __shared__ float tile[32][33];
  int bid = blockIdx.x;
  const float* in; bh* out; int Ncol, R, bx, by;
  if (bid < 1024)      { in = Wv; out = WvT; Ncol = DIM; R = DIM;
                         bx = bid & 31; by = bid >> 5; }
  else if (bid < 5120) { int b = bid - 1024; in = W1; out = W1T; Ncol = HID; R = 2 * DIM;
                         bx = b & 63; by = b >> 6; }
  else                 { int b = bid - 5120; in = W2; out = W2T; Ncol = TOK; R = HID;
                         bx = b & 127; by = b >> 7; }
  int nb = bx * 32, rb = by * 32;
  int tx = threadIdx.x, ty = threadIdx.y;  // block (32,8)
#pragma unroll
  for (int j = 0; j < 32; j += 8)
    tile[ty + j][tx] = in[(size_t)(rb + ty + j) * Ncol + nb + tx];
  __syncthreads();
#pragma unroll
  for (int j = 0; j < 32; j += 8)
    out[(size_t)(nb + ty + j) * R + rb + tx] = (bh)tile[tx][ty + j];
}

// ---------------- GEMM: C = act(A @ BT^T + bias), 16x16x32 MFMA ------------
// (m97-class structure; used for the smaller GEMMs)
template <int BN, bool RELU, bool TROUT, bool EXPS, typename OutT>
__global__ __launch_bounds__(128, 2) void gemm_bt(const bh* __restrict__ A,
                                                  const bh* __restrict__ BT,
                                                  const float* __restrict__ bias,
                                                  OutT* __restrict__ C,
                                                  float* __restrict__ rowsum,
                                                  int K, int lda, int ldbt, int ldc) {
  constexpr int NT = BN / 16;          // 8 (BN=128) or 4 (BN=64)
  __shared__ bh As[128 * 64];          // 16 KB
  __shared__ bh Bs[BN * 64];           // 16 or 8 KB
  const int t = threadIdx.x;
  const int id = blockIdx.x;
  const int bm = (id & 31) * 128, bn = (id >> 5) * BN;

  const int sr = t >> 3;               // staging row-in-group
  const int c8 = ((t & 7) ^ (sr & 7)) * 8;
  const bh* gA = A + (size_t)(bm + sr) * lda + c8;
  const bh* gB = BT + (size_t)(bn + sr) * ldbt + c8;
  bh* sA = As + t * 8;
  bh* sB = Bs + t * 8;

  const int lane = t & 63, w = t >> 6;
  const int lc = lane & 15, q = lane >> 4;

  v4f acc[4][NT] = {};
  for (int k0 = 0; k0 < K; k0 += 64) {
#pragma unroll
    for (int j = 0; j < 8; ++j)
      gl_lds16(gA + k0 + j * 16 * lda, sA + j * 1024);
#pragma unroll
    for (int j = 0; j < NT; ++j)
      gl_lds16(gB + k0 + j * 16 * ldbt, sB + j * 1024);
    __syncthreads();
#pragma unroll
    for (int h = 0; h < 2; ++h) {
      const int off = ((h * 4 + q) ^ (lc & 7)) * 8;
      v8bf af[4], bfr[NT];
#pragma unroll
      for (int mt = 0; mt < 4; ++mt)
        af[mt] = *(const v8bf*)(As + (w * 64 + mt * 16 + lc) * 64 + off);
#pragma unroll
      for (int nt = 0; nt < NT; ++nt)
        bfr[nt] = *(const v8bf*)(Bs + (nt * 16 + lc) * 64 + off);
#pragma unroll
      for (int mt = 0; mt < 4; ++mt)
#pragma unroll
        for (int nt = 0; nt < NT; ++nt)
          acc[mt][nt] = __builtin_amdgcn_mfma_f32_16x16x32_bf16(af[mt], bfr[nt], acc[mt][nt], 0, 0, 0);
    }
    __syncthreads();
  }

  // C/D layout: col = lane&15, row = q*4 + r  (m89-verified)
  const int r4 = q * 4;
  if (EXPS) {
    float bbv[NT];
#pragma unroll
    for (int nt = 0; nt < NT; ++nt) bbv[nt] = bias ? bias[bn + nt * 16 + lc] : 0.0f;
#pragma unroll
    for (int mt = 0; mt < 4; ++mt) {
#pragma unroll
      for (int r = 0; r < 4; ++r) {
        int row = bm + w * 64 + mt * 16 + r4 + r;
        float rs = 0.0f;
#pragma unroll
        for (int nt = 0; nt < NT; ++nt) {
          float val = __expf(acc[mt][nt][r] + bbv[nt]);
          rs += val;
          C[(size_t)row * ldc + bn + nt * 16 + lc] = (OutT)val;
        }
        rs += __shfl_xor(rs, 1);
        rs += __shfl_xor(rs, 2);
        rs += __shfl_xor(rs, 4);
        rs += __shfl_xor(rs, 8);
        if (lc == 0) atomicAdd(rowsum + row, rs);
      }
    }
  } else {
#pragma unroll
    for (int mt = 0; mt < 4; ++mt) {
      int row0 = bm + w * 64 + mt * 16 + r4;
#pragma unroll
      for (int nt = 0; nt < NT; ++nt) {
        int col = bn + nt * 16 + lc;
        float bb = bias ? bias[col] : 0.0f;
#pragma unroll
        for (int r = 0; r < 4; ++r) {
          float val = acc[mt][nt][r] + bb;
          if (RELU) val = fmaxf(val, 0.0f);
          if (TROUT) C[(size_t)col * ldc + (row0 + r)] = (OutT)val;
          else       C[(size_t)(row0 + r) * ldc + col] = (OutT)val;
        }
      }
    }
  }
}

// ---------------- gemm_exp256: scr = exp(hid @ W2T^T + b2) -----------------
// Faithful m201 8-phase template. BM=BN=256, BK=64, 512 thr = 8 waves (2Mx4N),
// wave tile 128x64, acc[8][4]. LDS: 2 dbuf x (32KB A + 32KB B) = 128 KB.
// K=2048 -> 32 K-tiles; tile t in buf[t&1]; 4 quadrant-phases per K-tile:
//   ph1: read A-lo(8)+B-lo(4) | stage B2,B3(t+1)->buf^1 | bar | MFMA Q(lo,lo)
//   ph2: read B-hi(4)         | stage A0,A2(t+2)->buf   | bar | MFMA Q(lo,hi)
//   ph3: read A-hi(8)         | stage B0,B1(t+2)->buf   | bar | MFMA Q(hi,lo)
//   ph4: (0 reads)            | stage A1,A3(t+2)->buf   | bar | MFMA Q(hi,hi)
//        vmcnt(6) | bar
// Every stage overwrites a region whose last ds_read finished >=1 barrier
// earlier (A0/A2 free after ph1, B fully free after ph2, A1/A3 after ph3).
// Ledger: 2 gl_lds/phase/wave; vmcnt(6) at ph4(t) retires EXACTLY tile t+2
// (its newest-6 = tile t+3's first 6), so each K-tile is fully resident one
// tile ahead of its reads; loads stay in flight across barriers (T4).
// Swizzle (G4 canonical for 128B rows): phys 16B-chunk = logical ^ (row&7),
// inverse-applied on the global source (lane-linear gl_lds dest), same XOR
// on ds_read. Tail: ph4(30) vmcnt(0); tile31 no stages/waits.
__global__ __launch_bounds__(512, 2) void gemm_exp256(const bh* __restrict__ A,
                                                      const bh* __restrict__ BT,
                                                      const float* __restrict__ bias,
                                                      bh* __restrict__ C,
                                                      float* __restrict__ rowsum) {
  __shared__ bh As[2][16384];          // [buf][256 rows * 64 k] = 2 x 32 KB
  __shared__ bh Bs[2][16384];
  const int t = threadIdx.x;
  const int id = blockIdx.x;           // 0..255, grid == CU count
  const int bm = (id & 15) * 256, bn = (id >> 4) * 256;
  const int lane = t & 63, w = t >> 6;
  const int wm = (w >> 2) * 128, wn = (w & 3) * 64;
  const int lc = lane & 15, q = lane >> 4;
  const int e0 = q ^ (lc & 7);         // swizzled chunk base for ds_read

  // staging: thread t covers row (t>>3) of a 64-row chunk, phys chunk t&7;
  // source logical chunk = (t&7) ^ ((t>>3)&7)  [inverse of read swizzle]
  const int srow = t >> 3;
  const int schunk = (t & 7) ^ (srow & 7);
  const bh* gA = A + (size_t)(bm + srow) * HID + schunk * 8;
  const bh* gB = BT + (size_t)(bn + srow) * HID + schunk * 8;
  bh* sA = &As[0][0] + t * 8;
  bh* sB = &Bs[0][0] + t * 8;

  v4f acc[8][4] = {};

#define STG_A(kt, c, buf) \
  gl_lds16(gA + (size_t)(kt) * 64 + (size_t)((c) * 64) * HID, sA + (buf) * 16384 + (c) * 4096)
#define STG_B(kt, c, buf) \
  gl_lds16(gB + (size_t)(kt) * 64 + (size_t)((c) * 64) * HID, sB + (buf) * 16384 + (c) * 4096)

#define TILE64(kt, buf, STG1, STG23, WM)                                        \
  do {                                                                          \
    const bh* ab = &As[buf][0];                                                 \
    const bh* bb = &Bs[buf][0];                                                 \
    v8bf alo[4][2], ahi[4][2], blo[2][2], bhi2[2][2];                           \
    /* ---- ph1 ---- */                                                         \
    _Pragma("unroll") for (int mt = 0; mt < 4; ++mt)                            \
      _Pragma("unroll") for (int kk = 0; kk < 2; ++kk)                          \
        alo[mt][kk] = *(const v8bf*)(ab + (wm + mt * 16 + lc) * 64 +            \
                                     ((e0 ^ (kk << 2)) << 3));                  \
    _Pragma("unroll") for (int nt = 0; nt < 2; ++nt)                            \
      _Pragma("unroll") for (int kk = 0; kk < 2; ++kk)                          \
        blo[nt][kk] = *(const v8bf*)(bb + (wn + nt * 16 + lc) * 64 +            \
                                     ((e0 ^ (kk << 2)) << 3));                  \
    if (STG1) { STG_B((kt) + 1, 2, (buf) ^ 1); STG_B((kt) + 1, 3, (buf) ^ 1); } \
    __builtin_amdgcn_s_barrier();                                               \
    asm volatile("s_waitcnt lgkmcnt(0)" ::: "memory");                          \
    __builtin_amdgcn_s_setprio(1);                                              \
    _Pragma("unroll") for (int mt = 0; mt < 4; ++mt)                            \
      _Pragma("unroll") for (int nt = 0; nt < 2; ++nt)                          \
        _Pragma("unroll") for (int kk = 0; kk < 2; ++kk)                        \
          acc[mt][nt] = __builtin_amdgcn_mfma_f32_16x16x32_bf16(                \
              alo[mt][kk], blo[nt][kk], acc[mt][nt], 0, 0, 0);                  \
    __builtin_amdgcn_s_setprio(0);                                              \
    __builtin_amdgcn_s_barrier();                                               \
    /* ---- ph2 ---- */                                                         \
    _Pragma("unroll") for (int nt = 0; nt < 2; ++nt)                            \
      _Pragma("unroll") for (int kk = 0; kk < 2; ++kk)                          \
        bhi2[nt][kk] = *(const v8bf*)(bb + (wn + 32 + nt * 16 + lc) * 64 +      \
                                      ((e0 ^ (kk << 2)) << 3));                 \
    if (STG23) { STG_A((kt) + 2, 0, buf); STG_A((kt) + 2, 2, buf); }            \
    __builtin_amdgcn_s_barrier();                                               \
    asm volatile("s_waitcnt lgkmcnt(0)" ::: "memory");                          \
    __builtin_amdgcn_s_setprio(1);                                              \
    _Pragma("unroll") for (int mt = 0; mt < 4; ++mt)                            \
      _Pragma("unroll") for (int nt = 0; nt < 2; ++nt)                          \
        _Pragma("unroll") for (int kk = 0; kk < 2; ++kk)                        \
          acc[mt][2 + nt] = __builtin_amdgcn_mfma_f32_16x16x32_bf16(            \
              alo[mt][kk], bhi2[nt][kk], acc[mt][2 + nt], 0, 0, 0);             \
    __builtin_amdgcn_s_setprio(0);                                              \
    __builtin_amdgcn_s_barrier();                                               \
    /* ---- ph3 ---- */                                                         \
    _Pragma("unroll") for (int mt = 0; mt < 4; ++mt)                            \
      _Pragma("unroll") for (int kk = 0; kk < 2; ++kk)                          \
        ahi[mt][kk] = *(const v8bf*)(ab + (wm + 64 + mt * 16 + lc) * 64 +       \
                                     ((e0 ^ (kk << 2)) << 3));                  \
    if (STG23) { STG_B((kt) + 2, 0, buf); STG_B((kt) + 2, 1, buf); }            \
    __builtin_amdgcn_s_barrier();                                               \
    asm volatile("s_waitcnt lgkmcnt(0)" ::: "memory");                          \
    __builtin_amdgcn_s_setprio(1);                                              \
    _Pragma("unroll") for (int mt = 0; mt < 4; ++mt)                            \
      _Pragma("unroll") for (int nt = 0; nt < 2; ++nt)                          \
        _Pragma("unroll") for (int kk = 0; kk < 2; ++kk)                        \
          acc[4 + mt][nt] = __builtin_amdgcn_mfma_f32_16x16x32_bf16(            \
              ahi[mt][kk], blo[nt][kk], acc[4 + mt][nt], 0, 0, 0);              \
    __builtin_amdgcn_s_setprio(0);                                              \
    __builtin_amdgcn_s_barrier();                                               \
    /* ---- ph4 ---- */                                                         \
    if (STG23) { STG_A((kt) + 2, 1, buf); STG_A((kt) + 2, 3, buf); }            \
    __builtin_amdgcn_s_barrier();                                               \
    __builtin_amdgcn_s_setprio(1);                                              \
    _Pragma("unroll") for (int mt = 0; mt < 4; ++mt)                            \
      _Pragma("unroll") for (int nt = 0; nt < 2; ++nt)                          \
        _Pragma("unroll") for (int kk = 0; kk < 2; ++kk)                        \
          acc[4 + mt][2 + nt] = __builtin_amdgcn_mfma_f32_16x16x32_bf16(        \
              ahi[mt][kk], bhi2[nt][kk], acc[4 + mt][2 + nt], 0, 0, 0);         \
    __builtin_amdgcn_s_setprio(0);                                              \
    if ((WM) == 1) asm volatile("s_waitcnt vmcnt(6)" ::: "memory");             \
    if ((WM) == 2) asm volatile("s_waitcnt vmcnt(0)" ::: "memory");             \
    __builtin_amdgcn_s_barrier();                                               \
  } while (0)

  // prologue: tile0 fully (8), then tile1 minus its B2,B3 (6);
  // vmcnt(6) retires exactly tile0.
  STG_A(0, 0, 0); STG_A(0, 1, 0); STG_A(0, 2, 0); STG_A(0, 3, 0);
  STG_B(0, 0, 0); STG_B(0, 1, 0); STG_B(0, 2, 0); STG_B(0, 3, 0);
  STG_A(1, 0, 1); STG_A(1, 2, 1); STG_B(1, 0, 1); STG_B(1, 1, 1);
  STG_A(1, 1, 1); STG_A(1, 3, 1);
  asm volatile("s_waitcnt vmcnt(6)" ::: "memory");
  __builtin_amdgcn_s_barrier();

  for (int tp = 0; tp < 15; ++tp) {
    const int kt = tp * 2;
    TILE64(kt, 0, 1, 1, 1);
    TILE64(kt + 1, 1, 1, 1, 1);
  }
  TILE64(30, 0, 1, 0, 2);   // stages B2,B3(31); vmcnt(0) retires tile 31
  TILE64(31, 1, 0, 0, 0);   // bare

#undef TILE64
#undef STG_A
#undef STG_B

  // epilogue: val = exp(acc + bias); store bf16; rowsum via 16-lane reduce
  const int r4 = q * 4;
  float bbv[4];
#pragma unroll
  for (int nt = 0; nt < 4; ++nt) bbv[nt] = bias[bn + wn + nt * 16 + lc];
#pragma unroll
  for (int mt = 0; mt < 8; ++mt) {
#pragma unroll
    for (int r = 0; r < 4; ++r) {
      int row = bm + wm + mt * 16 + r4 + r;
      float rs = 0.0f;
#pragma unroll
      for (int nt = 0; nt < 4; ++nt) {
        float val = __expf(acc[mt][nt][r] + bbv[nt]);
        rs += val;
        C[(size_t)row * TOK + bn + wn + nt * 16 + lc] = (bh)val;
      }
      rs += __shfl_xor(rs, 1);
      rs += __shfl_xor(rs, 2);
      rs += __shfl_xor(rs, 4);
      rs += __shfl_xor(rs, 8);
      if (lc == 0) atomicAdd(rowsum + row, rs);
    }
  }
}

// ---------------- GEMM4: part = expP @ V via split-K, 16x16x32 -------------
// 256-thread blocks (2x2 waves of 64x64), tile 128x128, BK=64, split-K=2.
__global__ __launch_bounds__(256, 4) void gemm4_split(const bh* __restrict__ A,
                                                      const bh* __restrict__ BT,
                                                      float* __restrict__ C0,
                                                      float* __restrict__ C1) {
  __shared__ bh As[128 * 64];          // 16 KB
  __shared__ bh Bs[128 * 64];          // 16 KB
  const int t = threadIdx.x;
  const int id = blockIdx.x;           // 0..255
  const int bm = (id & 31) * 128, bn = (id >> 5) * 128;
  const int kbeg = blockIdx.y * (TOK / 2);

  const int sr = t >> 3;               // 0..31
  const int c8 = ((t & 7) ^ (sr & 7)) * 8;
  const bh* gA = A + (size_t)(bm + sr) * TOK + kbeg + c8;
  const bh* gB = BT + (size_t)(bn + sr) * TOK + kbeg + c8;
  bh* sA = As + t * 8;
  bh* sB = Bs + t * 8;

  const int lane = t & 63, w = t >> 6;
  const int wm = (w >> 1) * 64, wn = (w & 1) * 64;
  const int lc = lane & 15, q = lane >> 4;

  v4f acc[4][4] = {};
  for (int k0 = 0; k0 < TOK / 2; k0 += 64) {
#pragma unroll
    for (int j = 0; j < 4; ++j) {
      gl_lds16(gA + k0 + (size_t)(j * 32) * TOK, sA + j * 2048);
      gl_lds16(gB + k0 + (size_t)(j * 32) * TOK, sB + j * 2048);
    }
    __syncthreads();
#pragma unroll
    for (int h = 0; h < 2; ++h) {
      const int off = ((h * 4 + q) ^ (lc & 7)) * 8;
      v8bf af[4], bfr[4];
#pragma unroll
      for (int mt = 0; mt < 4; ++mt)
        af[mt] = *(const v8bf*)(As + (wm + mt * 16 + lc) * 64 + off);
#pragma unroll
      for (int nt = 0; nt < 4; ++nt)
        bfr[nt] = *(const v8bf*)(Bs + (wn + nt * 16 + lc) * 64 + off);
#pragma unroll
      for (int mt = 0; mt < 4; ++mt)
#pragma unroll
        for (int nt = 0; nt < 4; ++nt)
          acc[mt][nt] = __builtin_amdgcn_mfma_f32_16x16x32_bf16(af[mt], bfr[nt], acc[mt][nt], 0, 0, 0);
    }
    __syncthreads();
  }

  float* C = blockIdx.y ? C1 : C0;
  const int r4 = q * 4;
#pragma unroll
  for (int mt = 0; mt < 4; ++mt) {
    int row0 = bm + wm + mt * 16 + r4;
#pragma unroll
    for (int nt = 0; nt < 4; ++nt) {
      int col = bn + wn + nt * 16 + lc;
#pragma unroll
      for (int r = 0; r < 4; ++r)
        C[(size_t)(row0 + r) * DIM + col] = acc[mt][nt][r];
    }
  }
}

// ---------------- finalize: out = (p0 + p1) / rowsum[row] ------------------
__global__ __launch_bounds__(256) void finalize(const float* __restrict__ p0,
                                                const float* __restrict__ p1,
                                                const float* __restrict__ rowsum,
                                                float* __restrict__ out) {
  size_t i = ((size_t)blockIdx.x * 256 + threadIdx.x) * 4;
  int row = (int)(i >> 10);            // DIM = 1024
  float inv = 1.0f / rowsum[row];
  float4 a = *(const float4*)(p0 + i);
  float4 b = *(const float4*)(p1 + i);
  float4 o;
  o.x = (a.x + b.x) * inv; o.y = (a.y + b.y) * inv;
  o.z = (a.z + b.z) * inv; o.w = (a.w + b.w) * inv;
  *(float4*)(out + i) = o;
}

extern "C" void kernel_launch(void* const* d_in, const int* in_sizes, int n_in,
                              void* d_out, int out_size, void* d_ws, size_t ws_size,
                              hipStream_t stream) {
  (void)in_sizes; (void)n_in; (void)out_size; (void)ws_size;
  const float* X  = (const float*)d_in[0];
  // d_in[1] = mask, unused by the module
  const float* Wv = (const float*)d_in[2];
  const float* bv = (const float*)d_in[3];
  const float* W1 = (const float*)d_in[4];
  const float* b1 = (const float*)d_in[5];
  const float* W2 = (const float*)d_in[6];
  const float* b2 = (const float*)d_in[7];
  float* out = (float*)d_out;

  char* ws = (char*)d_ws;
  bh* featb = (bh*)(ws);                       // 4096 x 2048 bf16 : 16 MiB
  bh* WvT   = (bh*)(ws + (16u << 20));         // 1024 x 1024      :  2 MiB
  bh* W1T   = (bh*)(ws + (18u << 20));         // 2048 x 2048      :  8 MiB
  bh* W2T   = (bh*)(ws + (26u << 20));         // 4096 x 2048      : 16 MiB
  bh* Vt    = (bh*)(ws + (42u << 20));         // 1024 x 4096      :  8 MiB
  bh* hid   = (bh*)(ws + (50u << 20));         // 4096 x 2048      : 16 MiB
  bh* scr   = (bh*)(ws + (66u << 20));         // 4096 x 4096 bf16 : 32 MiB (exp scores)
  float* S  = (float*)(ws + (98u << 20));      // 1024 fp32 (4 KB)
  float* rowsum = (float*)(ws + (98u << 20) + 4096);  // 4096 fp32 (16 KB)
  // split-K partials: part0 reuses featb region (dead after gemm2),
  // part1 reuses W2T region (dead after gemm3). 16 MiB fp32 each.
  float* part0 = (float*)(ws);
  float* part1 = (float*)(ws + (26u << 20));

  hipError_t e = hipMemsetAsync(S, 0, 4096 + 4096 * sizeof(float), stream);
  (void)e;
  prep_x_colsum<<<dim3(DIM / 512, TOK / 16), 256, 0, stream>>>(X, featb, S);
  prep_loo<<<dim3((TOK * DIM) / 1024), 256, 0, stream>>>(X, S, featb);
  transpose_all<<<dim3(1024 + 4096 + 8192), dim3(32, 8), 0, stream>>>(
      Wv, W1, W2, WvT, W1T, W2T);

  // V^T = (feat_left @ Wv + bv)^T  -> Vt (1024 x 4096, ld 4096)
  gemm_bt<64, false, true, false, bh><<<dim3(32 * (DIM / 64)), 128, 0, stream>>>(
      featb, WvT, bv, Vt, nullptr, DIM, 2 * DIM, DIM, TOK);
  // hid = relu(feat @ W1 + b1)
  gemm_bt<128, true, false, false, bh><<<dim3(32 * (HID / 128)), 128, 0, stream>>>(
      featb, W1T, b1, hid, nullptr, 2 * DIM, 2 * DIM, 2 * DIM, HID);
  // scr = exp(hid @ W2 + b2) [unnormalized softmax numerator] + rowsum
  // 256^2-tile faithful 8-phase kernel: grid 256 == CU count, 512 thr, 128KB LDS
  gemm_exp256<<<dim3(256), 512, 0, stream>>>(hid, W2T, b2, scr, rowsum);
  // parts = scr @ V, split-K=2
  gemm4_split<<<dim3(256, 2), 256, 0, stream>>>(scr, Vt, part0, part1);
  // out = (part0 + part1) / rowsum
  finalize<<<dim3((TOK * DIM) / 1024), 256, 0, stream>>>(part0, part1, rowsum, out);
}

// Round 4
// 312.057 us; speedup vs baseline: 1.0593x; 1.0494x over previous
//
#include <hip/hip_runtime.h>
#include <hip/hip_bf16.h>

#define TOK 4096
#define DIM 1024
#define HID 2048
#define LN10K 9.210340371976184f

typedef __bf16 bh;
typedef __bf16 v8bf __attribute__((ext_vector_type(8)));
typedef float v4f __attribute__((ext_vector_type(4)));

typedef const __attribute__((address_space(1))) void* gvp;
typedef __attribute__((address_space(3))) void* svp;

__device__ __forceinline__ void gl_lds16(const bh* g, bh* s) {
  __builtin_amdgcn_global_load_lds((gvp)g, (svp)s, 16, 0, 0);
}

// ---------------- prep: cast X -> feat left half, colsum(E) ----------------
__global__ __launch_bounds__(256) void prep_x_colsum(const float* __restrict__ X,
                                                     bh* __restrict__ featb,
                                                     float* __restrict__ S) {
  int cp = blockIdx.x * 256 + threadIdx.x;      // column pair 0..511
  int c = cp * 2;
  int r0 = blockIdx.y * 16;
  float inv_denom = __expf(-(float)c * (LN10K / (float)DIM));
  float s0 = 0.f, s1 = 0.f;
#pragma unroll 4
  for (int r = r0; r < r0 + 16; ++r) {
    float2 x = *(const float2*)(X + (size_t)r * DIM + c);
    float sn, cs;
    __sincosf((float)r * inv_denom, &sn, &cs);
    s0 += sn * x.x;
    s1 += cs * x.y;
    bh pair[2] = {(bh)x.x, (bh)x.y};
    *(ushort2*)(featb + (size_t)r * (2 * DIM) + c) = *(ushort2*)pair;
  }
  atomicAdd(&S[c], s0);
  atomicAdd(&S[c + 1], s1);
}

// ---------------- prep: loo -> feat right half ----------------
__global__ __launch_bounds__(256) void prep_loo(const float* __restrict__ X,
                                                const float* __restrict__ S,
                                                bh* __restrict__ featb) {
  size_t e4 = ((size_t)blockIdx.x * 256 + threadIdx.x) * 4;  // over TOK*DIM
  int r = (int)(e4 >> 10);
  int c = (int)(e4 & 1023);
  float4 x = *(const float4*)(X + e4);
  float4 s = *(const float4*)(S + c);
  float id0 = __expf(-(float)c * (LN10K / (float)DIM));
  float id1 = __expf(-(float)(c + 2) * (LN10K / (float)DIM));
  float sn0, cs0, sn1, cs1;
  __sincosf((float)r * id0, &sn0, &cs0);
  __sincosf((float)r * id1, &sn1, &cs1);
  const float inv = 1.0f / (float)(TOK - 1);
  bh outv[4];
  outv[0] = (bh)((s.x - sn0 * x.x) * inv);
  outv[1] = (bh)((s.y - cs0 * x.y) * inv);
  outv[2] = (bh)((s.z - sn1 * x.z) * inv);
  outv[3] = (bh)((s.w - cs1 * x.w) * inv);
  *(ushort4*)(featb + (size_t)r * (2 * DIM) + DIM + c) = *(ushort4*)outv;
}

// ---------------- fused transpose+cast of all 3 weights (1 dispatch) -------
__global__ __launch_bounds__(256) void transpose_all(const float* __restrict__ Wv,
                                                     const float* __restrict__ W1,
                                                     const float* __restrict__ W2,
                                                     bh* __restrict__ WvT,
                                                     bh* __restrict__ W1T,
                                                     bh* __restrict__ W2T) {
  __shared__ float tile[32][33];
  int bid = blockIdx.x;
  const float* in; bh* out; int Ncol, R, bx, by;
  if (bid < 1024)      { in = Wv; out = WvT; Ncol = DIM; R = DIM;
                         bx = bid & 31; by = bid >> 5; }
  else if (bid < 5120) { int b = bid - 1024; in = W1; out = W1T; Ncol = HID; R = 2 * DIM;
                         bx = b & 63; by = b >> 6; }
  else                 { int b = bid - 5120; in = W2; out = W2T; Ncol = TOK; R = HID;
                         bx = b & 127; by = b >> 7; }
  int nb = bx * 32, rb = by * 32;
  int tx = threadIdx.x, ty = threadIdx.y;  // block (32,8)
#pragma unroll
  for (int j = 0; j < 32; j += 8)
    tile[ty + j][tx] = in[(size_t)(rb + ty + j) * Ncol + nb + tx];
  __syncthreads();
#pragma unroll
  for (int j = 0; j < 32; j += 8)
    out[(size_t)(nb + ty + j) * R + rb + tx] = (bh)tile[tx][ty + j];
}

// ---------------- GEMM: C = act(A @ BT^T + bias), 16x16x32 MFMA ------------
// m97-canonical config: 256 threads = 4 waves (2x2), block tile 128 x BN,
// BK=64, wave tile 64 x (BN/2), acc[4][BN/32] (64 VGPR at BN=128).
// vs previous 128-thr variant: doubles waves/CU at every grid (gemm2 was
// 1 wave/SIMD!), halves acc VGPR. Staging: global_load_lds w=16,
// lane-linear LDS, 16B-grain XOR swizzle row&7 (0 conflicts measured).
// EXPS: epilogue stores exp(score) + fp32 rowsum atomics (softmax
// normalization happens in finalize).
// TROUT: epilogue transposes the 64x128 C-tile through LDS (reuses As)
// and stores coalesced 256B row segments — replaces the old scattered
// per-element 2B stores (8KB lane stride).
template <int BN, bool RELU, bool TROUT, bool EXPS, typename OutT>
__global__ __launch_bounds__(256, 2) void gemm_bt(const bh* __restrict__ A,
                                                  const bh* __restrict__ BT,
                                                  const float* __restrict__ bias,
                                                  OutT* __restrict__ C,
                                                  float* __restrict__ rowsum,
                                                  int K, int lda, int ldbt, int ldc) {
  constexpr int NT = BN / 32;          // n-frags per wave: 4 (BN=128) or 2 (BN=64)
  __shared__ bh As[128 * 64];          // 16 KB
  __shared__ bh Bs[BN * 64];           // 16 or 8 KB
  const int t = threadIdx.x;
  const int id = blockIdx.x;
  const int bm = (id & 31) * 128, bn = (id >> 5) * BN;

  const int srow = t >> 3;             // staging row-in-group 0..31
  const int c8 = ((t & 7) ^ (srow & 7)) * 8;
  const bh* gA = A + (size_t)(bm + srow) * lda + c8;
  const bh* gB = BT + (size_t)(bn + srow) * ldbt + c8;
  bh* sA = As + t * 8;
  bh* sB = Bs + t * 8;

  const int lane = t & 63, w = t >> 6;
  const int wm = (w >> 1) * 64, wn = (w & 1) * (BN / 2);
  const int lc = lane & 15, q = lane >> 4;

  v4f acc[4][NT] = {};
  for (int k0 = 0; k0 < K; k0 += 64) {
#pragma unroll
    for (int j = 0; j < 4; ++j)
      gl_lds16(gA + k0 + j * 32 * lda, sA + j * 2048);
#pragma unroll
    for (int j = 0; j < BN / 32; ++j)
      gl_lds16(gB + k0 + j * 32 * ldbt, sB + j * 2048);
    __syncthreads();
#pragma unroll
    for (int h = 0; h < 2; ++h) {
      const int off = ((h * 4 + q) ^ (lc & 7)) * 8;
      v8bf af[4], bfr[NT];
#pragma unroll
      for (int mt = 0; mt < 4; ++mt)
        af[mt] = *(const v8bf*)(As + (wm + mt * 16 + lc) * 64 + off);
#pragma unroll
      for (int nt = 0; nt < NT; ++nt)
        bfr[nt] = *(const v8bf*)(Bs + (wn + nt * 16 + lc) * 64 + off);
#pragma unroll
      for (int mt = 0; mt < 4; ++mt)
#pragma unroll
        for (int nt = 0; nt < NT; ++nt)
          acc[mt][nt] = __builtin_amdgcn_mfma_f32_16x16x32_bf16(af[mt], bfr[nt], acc[mt][nt], 0, 0, 0);
    }
    __syncthreads();
  }

  // C/D layout: col = lane&15, row = q*4 + r  (m89-verified)
  const int r4 = q * 4;
  if (EXPS) {
    float bbv[NT];
#pragma unroll
    for (int nt = 0; nt < NT; ++nt)
      bbv[nt] = bias ? bias[bn + wn + nt * 16 + lc] : 0.0f;
#pragma unroll
    for (int mt = 0; mt < 4; ++mt) {
#pragma unroll
      for (int r = 0; r < 4; ++r) {
        int row = bm + wm + mt * 16 + r4 + r;
        float rs = 0.0f;
#pragma unroll
        for (int nt = 0; nt < NT; ++nt) {
          float val = __expf(acc[mt][nt][r] + bbv[nt]);
          rs += val;
          C[(size_t)row * ldc + bn + wn + nt * 16 + lc] = (OutT)val;
        }
        rs += __shfl_xor(rs, 1);
        rs += __shfl_xor(rs, 2);
        rs += __shfl_xor(rs, 4);
        rs += __shfl_xor(rs, 8);
        if (lc == 0) atomicAdd(rowsum + row, rs);
      }
    }
  } else if (TROUT) {
    // transpose 64(col) x 128(row) tile through LDS (reuse As: 8192 bh),
    // then coalesced 16B stores: each output row = 256B contiguous.
    bh* trs = As;  // safe: k-loop ended with __syncthreads after all reads
#pragma unroll
    for (int mt = 0; mt < 4; ++mt) {
#pragma unroll
      for (int nt = 0; nt < NT; ++nt) {
        int cl = wn + nt * 16 + lc;          // 0..63 (BN=64)
        float bb = bias ? bias[bn + cl] : 0.0f;
#pragma unroll
        for (int r = 0; r < 4; ++r) {
          float val = acc[mt][nt][r] + bb;
          if (RELU) val = fmaxf(val, 0.0f);
          trs[cl * 128 + (wm + mt * 16 + r4 + r)] = (bh)val;
        }
      }
    }
    __syncthreads();
#pragma unroll
    for (int p = 0; p < 4; ++p) {
      int chunk = p * 256 + t;               // 0..1023 over 64x128 tile
      int vr = chunk >> 4, sc = chunk & 15;  // row 0..63, 16B seg 0..15
      *(v8bf*)((bh*)C + (size_t)(bn + vr) * ldc + bm + sc * 8) =
          *(const v8bf*)(trs + vr * 128 + sc * 8);
    }
  } else {
#pragma unroll
    for (int mt = 0; mt < 4; ++mt) {
      int row0 = bm + wm + mt * 16 + r4;
#pragma unroll
      for (int nt = 0; nt < NT; ++nt) {
        int col = bn + wn + nt * 16 + lc;
        float bb = bias ? bias[col] : 0.0f;
#pragma unroll
        for (int r = 0; r < 4; ++r) {
          float val = acc[mt][nt][r] + bb;
          if (RELU) val = fmaxf(val, 0.0f);
          C[(size_t)(row0 + r) * ldc + col] = (OutT)val;
        }
      }
    }
  }
}

// ---------------- GEMM4: part = expP @ V via split-K, 16x16x32 -------------
// 256-thread blocks (2x2 waves of 64x64), tile 128x128, BK=64, split-K=2.
__global__ __launch_bounds__(256, 4) void gemm4_split(const bh* __restrict__ A,
                                                      const bh* __restrict__ BT,
                                                      float* __restrict__ C0,
                                                      float* __restrict__ C1) {
  __shared__ bh As[128 * 64];          // 16 KB
  __shared__ bh Bs[128 * 64];          // 16 KB
  const int t = threadIdx.x;
  const int id = blockIdx.x;           // 0..255
  const int bm = (id & 31) * 128, bn = (id >> 5) * 128;
  const int kbeg = blockIdx.y * (TOK / 2);

  const int sr = t >> 3;               // 0..31
  const int c8 = ((t & 7) ^ (sr & 7)) * 8;
  const bh* gA = A + (size_t)(bm + sr) * TOK + kbeg + c8;
  const bh* gB = BT + (size_t)(bn + sr) * TOK + kbeg + c8;
  bh* sA = As + t * 8;
  bh* sB = Bs + t * 8;

  const int lane = t & 63, w = t >> 6;
  const int wm = (w >> 1) * 64, wn = (w & 1) * 64;
  const int lc = lane & 15, q = lane >> 4;

  v4f acc[4][4] = {};
  for (int k0 = 0; k0 < TOK / 2; k0 += 64) {
#pragma unroll
    for (int j = 0; j < 4; ++j) {
      gl_lds16(gA + k0 + (size_t)(j * 32) * TOK, sA + j * 2048);
      gl_lds16(gB + k0 + (size_t)(j * 32) * TOK, sB + j * 2048);
    }
    __syncthreads();
#pragma unroll
    for (int h = 0; h < 2; ++h) {
      const int off = ((h * 4 + q) ^ (lc & 7)) * 8;
      v8bf af[4], bfr[4];
#pragma unroll
      for (int mt = 0; mt < 4; ++mt)
        af[mt] = *(const v8bf*)(As + (wm + mt * 16 + lc) * 64 + off);
#pragma unroll
      for (int nt = 0; nt < 4; ++nt)
        bfr[nt] = *(const v8bf*)(Bs + (wn + nt * 16 + lc) * 64 + off);
#pragma unroll
      for (int mt = 0; mt < 4; ++mt)
#pragma unroll
        for (int nt = 0; nt < 4; ++nt)
          acc[mt][nt] = __builtin_amdgcn_mfma_f32_16x16x32_bf16(af[mt], bfr[nt], acc[mt][nt], 0, 0, 0);
    }
    __syncthreads();
  }

  float* C = blockIdx.y ? C1 : C0;
  const int r4 = q * 4;
#pragma unroll
  for (int mt = 0; mt < 4; ++mt) {
    int row0 = bm + wm + mt * 16 + r4;
#pragma unroll
    for (int nt = 0; nt < 4; ++nt) {
      int col = bn + wn + nt * 16 + lc;
#pragma unroll
      for (int r = 0; r < 4; ++r)
        C[(size_t)(row0 + r) * DIM + col] = acc[mt][nt][r];
    }
  }
}

// ---------------- finalize: out = (p0 + p1) / rowsum[row] ------------------
__global__ __launch_bounds__(256) void finalize(const float* __restrict__ p0,
                                                const float* __restrict__ p1,
                                                const float* __restrict__ rowsum,
                                                float* __restrict__ out) {
  size_t i = ((size_t)blockIdx.x * 256 + threadIdx.x) * 4;
  int row = (int)(i >> 10);            // DIM = 1024
  float inv = 1.0f / rowsum[row];
  float4 a = *(const float4*)(p0 + i);
  float4 b = *(const float4*)(p1 + i);
  float4 o;
  o.x = (a.x + b.x) * inv; o.y = (a.y + b.y) * inv;
  o.z = (a.z + b.z) * inv; o.w = (a.w + b.w) * inv;
  *(float4*)(out + i) = o;
}

extern "C" void kernel_launch(void* const* d_in, const int* in_sizes, int n_in,
                              void* d_out, int out_size, void* d_ws, size_t ws_size,
                              hipStream_t stream) {
  (void)in_sizes; (void)n_in; (void)out_size; (void)ws_size;
  const float* X  = (const float*)d_in[0];
  // d_in[1] = mask, unused by the module
  const float* Wv = (const float*)d_in[2];
  const float* bv = (const float*)d_in[3];
  const float* W1 = (const float*)d_in[4];
  const float* b1 = (const float*)d_in[5];
  const float* W2 = (const float*)d_in[6];
  const float* b2 = (const float*)d_in[7];
  float* out = (float*)d_out;

  char* ws = (char*)d_ws;
  bh* featb = (bh*)(ws);                       // 4096 x 2048 bf16 : 16 MiB
  bh* WvT   = (bh*)(ws + (16u << 20));         // 1024 x 1024      :  2 MiB
  bh* W1T   = (bh*)(ws + (18u << 20));         // 2048 x 2048      :  8 MiB
  bh* W2T   = (bh*)(ws + (26u << 20));         // 4096 x 2048      : 16 MiB
  bh* Vt    = (bh*)(ws + (42u << 20));         // 1024 x 4096      :  8 MiB
  bh* hid   = (bh*)(ws + (50u << 20));         // 4096 x 2048      : 16 MiB
  bh* scr   = (bh*)(ws + (66u << 20));         // 4096 x 4096 bf16 : 32 MiB (exp scores)
  float* S  = (float*)(ws + (98u << 20));      // 1024 fp32 (4 KB)
  float* rowsum = (float*)(ws + (98u << 20) + 4096);  // 4096 fp32 (16 KB)
  // split-K partials: part0 reuses featb region (dead after gemm2),
  // part1 reuses W2T region (dead after gemm3). 16 MiB fp32 each.
  float* part0 = (float*)(ws);
  float* part1 = (float*)(ws + (26u << 20));

  hipError_t e = hipMemsetAsync(S, 0, 4096 + 4096 * sizeof(float), stream);
  (void)e;
  prep_x_colsum<<<dim3(DIM / 512, TOK / 16), 256, 0, stream>>>(X, featb, S);
  prep_loo<<<dim3((TOK * DIM) / 1024), 256, 0, stream>>>(X, S, featb);
  transpose_all<<<dim3(1024 + 4096 + 8192), dim3(32, 8), 0, stream>>>(
      Wv, W1, W2, WvT, W1T, W2T);

  // V^T = (feat_left @ Wv + bv)^T  -> Vt (1024 x 4096, ld 4096)
  gemm_bt<64, false, true, false, bh><<<dim3(32 * (DIM / 64)), 256, 0, stream>>>(
      featb, WvT, bv, Vt, nullptr, DIM, 2 * DIM, DIM, TOK);
  // hid = relu(feat @ W1 + b1)
  gemm_bt<128, true, false, false, bh><<<dim3(32 * (HID / 128)), 256, 0, stream>>>(
      featb, W1T, b1, hid, nullptr, 2 * DIM, 2 * DIM, 2 * DIM, HID);
  // scr = exp(hid @ W2 + b2)  [unnormalized softmax numerator] + rowsum
  gemm_bt<128, false, false, true, bh><<<dim3(32 * (TOK / 128)), 256, 0, stream>>>(
      hid, W2T, b2, scr, rowsum, HID, HID, HID, TOK);
  // parts = scr @ V, split-K=2
  gemm4_split<<<dim3(256, 2), 256, 0, stream>>>(scr, Vt, part0, part1);
  // out = (part0 + part1) / rowsum
  finalize<<<dim3((TOK * DIM) / 1024), 256, 0, stream>>>(part0, part1, rowsum, out);
}